// Round 1
// baseline (1507.583 us; speedup 1.0000x reference)
//
#include <hip/hip_runtime.h>
#include <hip/hip_bf16.h>
#include <math.h>

// Problem constants
#define N_ROWS 16384   // B*T
#define DIM    256
#define KC     4096
#define TOPK   3

// Output flat offsets (floats)
#define O_LOSS   0
#define O_QUANT  1
#define O_PERP   12582913
#define O_AVGP   12582914
#define O_IDX    12587010
#define O_DIST   12636162
#define O_NCS    79745026
#define O_NEMAW  79749122
#define O_UPD    80797698

// ---------------------------------------------------------------- row norms
__global__ __launch_bounds__(256) void rownorm_kernel(
    const float* __restrict__ X, float* __restrict__ out, int rows)
{
    int wave = threadIdx.x >> 6;
    int lane = threadIdx.x & 63;
    int row  = blockIdx.x * 4 + wave;
    if (row >= rows) return;
    float4 v = *(const float4*)&X[(size_t)row * DIM + lane * 4];
    float s = v.x*v.x + v.y*v.y + v.z*v.z + v.w*v.w;
    #pragma unroll
    for (int off = 32; off; off >>= 1) s += __shfl_down(s, off);
    if (lane == 0) out[row] = s;
}

// ------------------------------------------------- init new_ema_w = 0.99*ema_w
__global__ __launch_bounds__(256) void scale_ema_kernel(
    const float* __restrict__ emaw, float* __restrict__ nemaw)
{
    int i = (blockIdx.x * 256 + threadIdx.x) * 4;  // covers KC*DIM exactly
    float4 v = *(const float4*)&emaw[i];
    v.x *= 0.99f; v.y *= 0.99f; v.z *= 0.99f; v.w *= 0.99f;
    *(float4*)&nemaw[i] = v;
}

// ---------------------------------------------------------------- fp32 GEMM
// dists[m,n] = xn[m] + en[n] - 2 * dot(X[m,:], E[n,:])
#define BM 128
#define BN 128
#define BK 8

__global__ __launch_bounds__(256) void gemm_dist_kernel(
    const float* __restrict__ A,   // [N_ROWS, DIM]
    const float* __restrict__ Bm,  // [KC, DIM]
    const float* __restrict__ xn,  // [N_ROWS]
    const float* __restrict__ en,  // [KC]
    float* __restrict__ dist)      // [N_ROWS, KC]
{
    __shared__ float As[BK][BM];
    __shared__ float Bs[BK][BN];

    const int tid = threadIdx.x;
    const int m0 = blockIdx.y * BM;
    const int n0 = blockIdx.x * BN;
    const int lr = tid >> 1;          // 0..127
    const int lc = (tid & 1) * 4;     // 0 or 4
    const int tx = tid & 15;
    const int ty = tid >> 4;

    float acc[8][8];
    #pragma unroll
    for (int i = 0; i < 8; i++)
        #pragma unroll
        for (int j = 0; j < 8; j++) acc[i][j] = 0.0f;

    const float* Arow = &A[(size_t)(m0 + lr) * DIM + lc];
    const float* Brow = &Bm[(size_t)(n0 + lr) * DIM + lc];

    for (int kt = 0; kt < DIM; kt += BK) {
        float4 av = *(const float4*)&Arow[kt];
        float4 bv = *(const float4*)&Brow[kt];
        As[lc + 0][lr] = av.x; As[lc + 1][lr] = av.y;
        As[lc + 2][lr] = av.z; As[lc + 3][lr] = av.w;
        Bs[lc + 0][lr] = bv.x; Bs[lc + 1][lr] = bv.y;
        Bs[lc + 2][lr] = bv.z; Bs[lc + 3][lr] = bv.w;
        __syncthreads();

        #pragma unroll
        for (int kk = 0; kk < BK; kk++) {
            float4 a0 = *(const float4*)&As[kk][ty * 4];
            float4 a1 = *(const float4*)&As[kk][ty * 4 + 64];
            float4 b0 = *(const float4*)&Bs[kk][tx * 4];
            float4 b1 = *(const float4*)&Bs[kk][tx * 4 + 64];
            float a[8] = {a0.x, a0.y, a0.z, a0.w, a1.x, a1.y, a1.z, a1.w};
            float b[8] = {b0.x, b0.y, b0.z, b0.w, b1.x, b1.y, b1.z, b1.w};
            #pragma unroll
            for (int i = 0; i < 8; i++)
                #pragma unroll
                for (int j = 0; j < 8; j++)
                    acc[i][j] = fmaf(a[i], b[j], acc[i][j]);
        }
        __syncthreads();
    }

    // epilogue
    float4 e0 = *(const float4*)&en[n0 + tx * 4];
    float4 e1 = *(const float4*)&en[n0 + 64 + tx * 4];
    float eb[8] = {e0.x, e0.y, e0.z, e0.w, e1.x, e1.y, e1.z, e1.w};

    #pragma unroll
    for (int i = 0; i < 8; i++) {
        int r = m0 + ((i < 4) ? (ty * 4 + i) : (64 + ty * 4 + (i - 4)));
        float xr = xn[r];
        float4 c0, c1;
        c0.x = xr + eb[0] - 2.0f * acc[i][0];
        c0.y = xr + eb[1] - 2.0f * acc[i][1];
        c0.z = xr + eb[2] - 2.0f * acc[i][2];
        c0.w = xr + eb[3] - 2.0f * acc[i][3];
        c1.x = xr + eb[4] - 2.0f * acc[i][4];
        c1.y = xr + eb[5] - 2.0f * acc[i][5];
        c1.z = xr + eb[6] - 2.0f * acc[i][6];
        c1.w = xr + eb[7] - 2.0f * acc[i][7];
        float* dr = &dist[(size_t)r * KC + n0 + tx * 4];
        *(float4*)&dr[0]  = c0;
        *(float4*)&dr[64] = c1;
    }
}

// ---------------------------------------------------------------- top-3
__device__ __forceinline__ bool vi_lt(float v, int i, float u, int j)
{
    return (v < u) || (v == u && i < j);
}

__global__ __launch_bounds__(256) void top3_kernel(
    const float* __restrict__ dist, int* __restrict__ idxw,
    float* __restrict__ out_idx, float* __restrict__ counts)
{
    int wave = threadIdx.x >> 6;
    int lane = threadIdx.x & 63;
    int row  = blockIdx.x * 4 + wave;
    if (row >= N_ROWS) return;
    const float* dr = dist + (size_t)row * KC;

    float v0 = INFINITY, v1 = INFINITY, v2 = INFINITY;
    int   i0 = 0x7fffffff, i1 = 0x7fffffff, i2 = 0x7fffffff;

    #pragma unroll 4
    for (int it = 0; it < 16; it++) {
        int c = (it * 64 + lane) * 4;
        float4 d = *(const float4*)&dr[c];
        float dv[4] = {d.x, d.y, d.z, d.w};
        #pragma unroll
        for (int q = 0; q < 4; q++) {
            float v = dv[q]; int ci = c + q;
            if (vi_lt(v, ci, v2, i2)) {
                v2 = v; i2 = ci;
                if (vi_lt(v2, i2, v1, i1)) { float tv = v1; int ti = i1; v1 = v2; i1 = i2; v2 = tv; i2 = ti; }
                if (vi_lt(v1, i1, v0, i0)) { float tv = v0; int ti = i0; v0 = v1; i0 = i1; v1 = tv; i1 = ti; }
            }
        }
    }

    // butterfly merge of sorted triples
    #pragma unroll
    for (int off = 1; off < 64; off <<= 1) {
        float u0 = __shfl_xor(v0, off), u1 = __shfl_xor(v1, off), u2 = __shfl_xor(v2, off);
        int   j0 = __shfl_xor(i0, off), j1 = __shfl_xor(i1, off), j2 = __shfl_xor(i2, off);
        float av[3] = {v0, v1, v2}; int ai[3] = {i0, i1, i2};
        float bv[3] = {u0, u1, u2}; int bi[3] = {j0, j1, j2};
        float rv[3]; int ri[3];
        int p = 0, q = 0;
        #pragma unroll
        for (int t = 0; t < 3; t++) {
            bool ta = vi_lt(av[p], ai[p], bv[q], bi[q]);
            rv[t] = ta ? av[p] : bv[q];
            ri[t] = ta ? ai[p] : bi[q];
            p += ta ? 1 : 0; q += ta ? 0 : 1;
        }
        v0 = rv[0]; v1 = rv[1]; v2 = rv[2];
        i0 = ri[0]; i1 = ri[1]; i2 = ri[2];
    }

    if (lane == 0) {
        int base = row * TOPK;
        idxw[base + 0] = i0; idxw[base + 1] = i1; idxw[base + 2] = i2;
        out_idx[base + 0] = (float)i0;
        out_idx[base + 1] = (float)i1;
        out_idx[base + 2] = (float)i2;
        atomicAdd(&counts[i0], 1.0f);
        atomicAdd(&counts[i1], 1.0f);
        atomicAdd(&counts[i2], 1.0f);
    }
}

// --------------------------------------- gather quant + loss + dw scatter
__global__ __launch_bounds__(64) void gather_kernel(
    const int* __restrict__ idxw, const float* __restrict__ E,
    const float* __restrict__ flat, float* __restrict__ quant_out,
    float* __restrict__ nemaw, float* __restrict__ scalars)
{
    int j = blockIdx.x;           // 0 .. N_ROWS*TOPK-1
    int n = j / 3;
    int code = idxw[j];
    int d4 = threadIdx.x * 4;

    float4 qv = *(const float4*)&E[(size_t)code * DIM + d4];
    float4 xv = *(const float4*)&flat[(size_t)n * DIM + d4];
    *(float4*)&quant_out[(size_t)j * DIM + d4] = qv;

    float dx = qv.x - xv.x, dy = qv.y - xv.y, dz = qv.z - xv.z, dw = qv.w - xv.w;
    float s = dx*dx + dy*dy + dz*dz + dw*dw;
    #pragma unroll
    for (int off = 32; off; off >>= 1) s += __shfl_down(s, off);
    if (threadIdx.x == 0) atomicAdd(&scalars[1], s);

    float* wp = &nemaw[(size_t)code * DIM + d4];
    atomicAdd(&wp[0], 0.01f * xv.x);
    atomicAdd(&wp[1], 0.01f * xv.y);
    atomicAdd(&wp[2], 0.01f * xv.z);
    atomicAdd(&wp[3], 0.01f * xv.w);
}

// ----------------------------------------- K-wise stage 1: pre, avg_probs
__global__ __launch_bounds__(256) void kstage1_kernel(
    const float* __restrict__ counts, const float* __restrict__ ecs,
    float* __restrict__ pre, float* __restrict__ avgp, float* __restrict__ scalars)
{
    int k = blockIdx.x * 256 + threadIdx.x;
    float cnt = counts[k];
    float pr = ecs[k] * 0.99f + 0.01f * cnt;
    pre[k] = pr;
    float p = cnt * (1.0f / (float)N_ROWS);
    avgp[k] = p;
    float ent = p * logf(p + 1e-10f);
    int lane = threadIdx.x & 63;
    #pragma unroll
    for (int off = 32; off; off >>= 1) {
        pr  += __shfl_down(pr, off);
        ent += __shfl_down(ent, off);
    }
    if (lane == 0) {
        atomicAdd(&scalars[0], pr);
        atomicAdd(&scalars[2], ent);
    }
}

// ----------------------------------------- K-wise stage 2: normalized new_cs
__global__ __launch_bounds__(256) void kstage2_kernel(
    const float* __restrict__ pre, const float* __restrict__ scalars,
    float* __restrict__ ncs)
{
    int k = blockIdx.x * 256 + threadIdx.x;
    float nt = scalars[0];
    ncs[k] = (pre[k] + 1e-5f) / (nt + (float)KC * 1e-5f) * nt;
}

// ------------------------------------------- updated = new_ema_w / new_cs
__global__ __launch_bounds__(256) void update_kernel(
    const float* __restrict__ nemaw, const float* __restrict__ ncs,
    float* __restrict__ upd)
{
    int i = (blockIdx.x * 256 + threadIdx.x) * 4;
    int row = i >> 8;  // DIM = 256
    float inv = ncs[row];
    float4 v = *(const float4*)&nemaw[i];
    v.x /= inv; v.y /= inv; v.z /= inv; v.w /= inv;
    *(float4*)&upd[i] = v;
}

// ------------------------------------------------------------- scalars
__global__ void final_kernel(const float* __restrict__ scalars, float* __restrict__ out)
{
    out[O_LOSS] = 0.25f * scalars[1] / (float)(N_ROWS * TOPK * DIM);
    out[O_PERP] = expf(-scalars[2]);
}

extern "C" void kernel_launch(void* const* d_in, const int* in_sizes, int n_in,
                              void* d_out, int out_size, void* d_ws, size_t ws_size,
                              hipStream_t stream)
{
    const float* inputs = (const float*)d_in[0];   // [16,1024,256]
    const float* emb    = (const float*)d_in[1];   // [4096,256]
    const float* ecs    = (const float*)d_in[2];   // [4096]
    const float* emaw   = (const float*)d_in[3];   // [4096,256]
    float* out = (float*)d_out;
    char* ws = (char*)d_ws;

    int*   idxw    = (int*)ws;                      // 49152 ints
    float* counts  = (float*)(ws + 196608);         // 4096 f
    float* pre     = (float*)(ws + 212992);         // 4096 f
    float* xn      = (float*)(ws + 229376);         // 16384 f
    float* en      = (float*)(ws + 294912);         // 4096 f
    float* scalars = (float*)(ws + 311296);         // [n_total, sqsum, entropy]

    hipMemsetAsync(counts, 0, KC * sizeof(float), stream);
    hipMemsetAsync(scalars, 0, 8 * sizeof(float), stream);

    rownorm_kernel<<<N_ROWS / 4, 256, 0, stream>>>(inputs, xn, N_ROWS);
    rownorm_kernel<<<KC / 4, 256, 0, stream>>>(emb, en, KC);
    scale_ema_kernel<<<(KC * DIM) / 1024, 256, 0, stream>>>(emaw, out + O_NEMAW);

    gemm_dist_kernel<<<dim3(KC / BN, N_ROWS / BM), 256, 0, stream>>>(
        inputs, emb, xn, en, out + O_DIST);

    top3_kernel<<<N_ROWS / 4, 256, 0, stream>>>(out + O_DIST, idxw, out + O_IDX, counts);

    gather_kernel<<<N_ROWS * TOPK, 64, 0, stream>>>(
        idxw, emb, inputs, out + O_QUANT, out + O_NEMAW, scalars);

    kstage1_kernel<<<KC / 256, 256, 0, stream>>>(counts, ecs, pre, out + O_AVGP, scalars);
    kstage2_kernel<<<KC / 256, 256, 0, stream>>>(pre, scalars, out + O_NCS);
    update_kernel<<<(KC * DIM) / 1024, 256, 0, stream>>>(out + O_NEMAW, out + O_NCS, out + O_UPD);
    final_kernel<<<1, 1, 0, stream>>>(scalars, out);
}

// Round 2
// 1128.595 us; speedup vs baseline: 1.3358x; 1.3358x over previous
//
#include <hip/hip_runtime.h>
#include <hip/hip_bf16.h>
#include <math.h>

// Problem constants
#define N_ROWS 16384   // B*T
#define DIM    256
#define KC     4096
#define TOPK   3

// Output flat offsets (floats)
#define O_LOSS   0
#define O_QUANT  1
#define O_PERP   12582913
#define O_AVGP   12582914
#define O_IDX    12587010
#define O_DIST   12636162
#define O_NCS    79745026
#define O_NEMAW  79749122
#define O_UPD    80797698

// ---------------------------------------------------------------- row norms
__global__ __launch_bounds__(256) void rownorm_kernel(
    const float* __restrict__ X, float* __restrict__ out, int rows)
{
    int wave = threadIdx.x >> 6;
    int lane = threadIdx.x & 63;
    int row  = blockIdx.x * 4 + wave;
    if (row >= rows) return;
    float4 v = *(const float4*)&X[(size_t)row * DIM + lane * 4];
    float s = v.x*v.x + v.y*v.y + v.z*v.z + v.w*v.w;
    #pragma unroll
    for (int off = 32; off; off >>= 1) s += __shfl_down(s, off);
    if (lane == 0) out[row] = s;
}

// ---------------------------------------------------------------- fp32 GEMM
// dists[m,n] = xn[m] + en[n] - 2 * dot(X[m,:], E[n,:])
#define BM 128
#define BN 128
#define BK 8

__global__ __launch_bounds__(256) void gemm_dist_kernel(
    const float* __restrict__ A,   // [N_ROWS, DIM]
    const float* __restrict__ Bm,  // [KC, DIM]
    const float* __restrict__ xn,  // [N_ROWS]
    const float* __restrict__ en,  // [KC]
    float* __restrict__ dist)      // [N_ROWS, KC]
{
    __shared__ float As[BK][BM];
    __shared__ float Bs[BK][BN];

    const int tid = threadIdx.x;
    const int m0 = blockIdx.y * BM;
    const int n0 = blockIdx.x * BN;
    const int lr = tid >> 1;          // 0..127
    const int lc = (tid & 1) * 4;     // 0 or 4
    const int tx = tid & 15;
    const int ty = tid >> 4;

    float acc[8][8];
    #pragma unroll
    for (int i = 0; i < 8; i++)
        #pragma unroll
        for (int j = 0; j < 8; j++) acc[i][j] = 0.0f;

    const float* Arow = &A[(size_t)(m0 + lr) * DIM + lc];
    const float* Brow = &Bm[(size_t)(n0 + lr) * DIM + lc];

    for (int kt = 0; kt < DIM; kt += BK) {
        float4 av = *(const float4*)&Arow[kt];
        float4 bv = *(const float4*)&Brow[kt];
        As[lc + 0][lr] = av.x; As[lc + 1][lr] = av.y;
        As[lc + 2][lr] = av.z; As[lc + 3][lr] = av.w;
        Bs[lc + 0][lr] = bv.x; Bs[lc + 1][lr] = bv.y;
        Bs[lc + 2][lr] = bv.z; Bs[lc + 3][lr] = bv.w;
        __syncthreads();

        #pragma unroll
        for (int kk = 0; kk < BK; kk++) {
            float4 a0 = *(const float4*)&As[kk][ty * 4];
            float4 a1 = *(const float4*)&As[kk][ty * 4 + 64];
            float4 b0 = *(const float4*)&Bs[kk][tx * 4];
            float4 b1 = *(const float4*)&Bs[kk][tx * 4 + 64];
            float a[8] = {a0.x, a0.y, a0.z, a0.w, a1.x, a1.y, a1.z, a1.w};
            float b[8] = {b0.x, b0.y, b0.z, b0.w, b1.x, b1.y, b1.z, b1.w};
            #pragma unroll
            for (int i = 0; i < 8; i++)
                #pragma unroll
                for (int j = 0; j < 8; j++)
                    acc[i][j] = fmaf(a[i], b[j], acc[i][j]);
        }
        __syncthreads();
    }

    float4 e0 = *(const float4*)&en[n0 + tx * 4];
    float4 e1 = *(const float4*)&en[n0 + 64 + tx * 4];
    float eb[8] = {e0.x, e0.y, e0.z, e0.w, e1.x, e1.y, e1.z, e1.w};

    #pragma unroll
    for (int i = 0; i < 8; i++) {
        int r = m0 + ((i < 4) ? (ty * 4 + i) : (64 + ty * 4 + (i - 4)));
        float xr = xn[r];
        float4 c0, c1;
        c0.x = xr + eb[0] - 2.0f * acc[i][0];
        c0.y = xr + eb[1] - 2.0f * acc[i][1];
        c0.z = xr + eb[2] - 2.0f * acc[i][2];
        c0.w = xr + eb[3] - 2.0f * acc[i][3];
        c1.x = xr + eb[4] - 2.0f * acc[i][4];
        c1.y = xr + eb[5] - 2.0f * acc[i][5];
        c1.z = xr + eb[6] - 2.0f * acc[i][6];
        c1.w = xr + eb[7] - 2.0f * acc[i][7];
        float* dr = &dist[(size_t)r * KC + n0 + tx * 4];
        *(float4*)&dr[0]  = c0;
        *(float4*)&dr[64] = c1;
    }
}

// ---------------------------------------------------------------- top-3
__device__ __forceinline__ bool vi_lt(float v, int i, float u, int j)
{
    return (v < u) || (v == u && i < j);
}

// one wave per row; accumulates the commitment-loss partial per block
// (loss = sum of the 3 smallest dists per row — no value atomics needed)
__global__ __launch_bounds__(256) void top3_kernel(
    const float* __restrict__ dist, int* __restrict__ idxw,
    float* __restrict__ out_idx, float* __restrict__ counts,
    float* __restrict__ loss_part)
{
    __shared__ float blk_loss;
    if (threadIdx.x == 0) blk_loss = 0.0f;
    __syncthreads();

    int wave = threadIdx.x >> 6;
    int lane = threadIdx.x & 63;
    int row  = blockIdx.x * 4 + wave;   // grid exact: N_ROWS/4 blocks
    const float* dr = dist + (size_t)row * KC;

    float v0 = INFINITY, v1 = INFINITY, v2 = INFINITY;
    int   i0 = 0x7fffffff, i1 = 0x7fffffff, i2 = 0x7fffffff;

    #pragma unroll 4
    for (int it = 0; it < 16; it++) {
        int c = (it * 64 + lane) * 4;
        float4 d = *(const float4*)&dr[c];
        float dv[4] = {d.x, d.y, d.z, d.w};
        #pragma unroll
        for (int q = 0; q < 4; q++) {
            float v = dv[q]; int ci = c + q;
            if (vi_lt(v, ci, v2, i2)) {
                v2 = v; i2 = ci;
                if (vi_lt(v2, i2, v1, i1)) { float tv = v1; int ti = i1; v1 = v2; i1 = i2; v2 = tv; i2 = ti; }
                if (vi_lt(v1, i1, v0, i0)) { float tv = v0; int ti = i0; v0 = v1; i0 = i1; v1 = tv; i1 = ti; }
            }
        }
    }

    #pragma unroll
    for (int off = 1; off < 64; off <<= 1) {
        float u0 = __shfl_xor(v0, off), u1 = __shfl_xor(v1, off), u2 = __shfl_xor(v2, off);
        int   j0 = __shfl_xor(i0, off), j1 = __shfl_xor(i1, off), j2 = __shfl_xor(i2, off);
        float av[3] = {v0, v1, v2}; int ai[3] = {i0, i1, i2};
        float bv[3] = {u0, u1, u2}; int bi[3] = {j0, j1, j2};
        float rv[3]; int ri[3];
        int p = 0, q = 0;
        #pragma unroll
        for (int t = 0; t < 3; t++) {
            bool ta = vi_lt(av[p], ai[p], bv[q], bi[q]);
            rv[t] = ta ? av[p] : bv[q];
            ri[t] = ta ? ai[p] : bi[q];
            p += ta ? 1 : 0; q += ta ? 0 : 1;
        }
        v0 = rv[0]; v1 = rv[1]; v2 = rv[2];
        i0 = ri[0]; i1 = ri[1]; i2 = ri[2];
    }

    if (lane == 0) {
        int base = row * TOPK;
        idxw[base + 0] = i0; idxw[base + 1] = i1; idxw[base + 2] = i2;
        out_idx[base + 0] = (float)i0;
        out_idx[base + 1] = (float)i1;
        out_idx[base + 2] = (float)i2;
        atomicAdd(&counts[i0], 1.0f);
        atomicAdd(&counts[i1], 1.0f);
        atomicAdd(&counts[i2], 1.0f);
        atomicAdd(&blk_loss, v0 + v1 + v2);   // LDS atomic, 4/block
    }
    __syncthreads();
    if (threadIdx.x == 0) loss_part[blockIdx.x] = blk_loss;
}

// -------------------------------------------- pure gather copy: quant = E[idx]
__global__ __launch_bounds__(256) void quant_copy_kernel(
    const int* __restrict__ idxw, const float* __restrict__ E,
    float* __restrict__ quant_out)
{
    int wave = threadIdx.x >> 6;
    int lane = threadIdx.x & 63;
    int j = blockIdx.x * 4 + wave;          // 0 .. N_ROWS*TOPK-1
    int code = idxw[j];
    float4 v = *(const float4*)&E[(size_t)code * DIM + lane * 4];
    *(float4*)&quant_out[(size_t)j * DIM + lane * 4] = v;
}

// ----------------------------------------- K-wise stage 1: avg_probs, sums
__global__ __launch_bounds__(256) void kstage1_kernel(
    const float* __restrict__ counts, const float* __restrict__ ecs,
    float* __restrict__ avgp, float* __restrict__ scalars)
{
    int k = blockIdx.x * 256 + threadIdx.x;
    float cnt = counts[k];
    float pr = ecs[k] * 0.99f + 0.01f * cnt;
    float p = cnt * (1.0f / (float)N_ROWS);
    avgp[k] = p;
    float ent = p * logf(p + 1e-10f);
    int lane = threadIdx.x & 63;
    #pragma unroll
    for (int off = 32; off; off >>= 1) {
        pr  += __shfl_down(pr, off);
        ent += __shfl_down(ent, off);
    }
    if (lane == 0) {
        atomicAdd(&scalars[0], pr);
        atomicAdd(&scalars[2], ent);
    }
}

// ------------------------- K-wise stage 2: normalized new_cs (recomputes pre)
__global__ __launch_bounds__(256) void kstage2_kernel(
    const float* __restrict__ counts, const float* __restrict__ ecs,
    const float* __restrict__ scalars, float* __restrict__ ncs)
{
    int k = blockIdx.x * 256 + threadIdx.x;
    float pre = ecs[k] * 0.99f + 0.01f * counts[k];
    float nt = scalars[0];
    ncs[k] = (pre + 1e-5f) / (nt + (float)KC * 1e-5f) * nt;
}

// ----------------------------------------- prefix scan of counts -> offsets
__global__ __launch_bounds__(1024) void scan_kernel(
    const float* __restrict__ counts, int* __restrict__ offsets)
{
    __shared__ int lds[1024];
    int t = threadIdx.x;
    int c[4]; int s = 0;
    #pragma unroll
    for (int q = 0; q < 4; q++) { c[q] = (int)(counts[t * 4 + q] + 0.5f); s += c[q]; }
    lds[t] = s;
    __syncthreads();
    for (int off = 1; off < 1024; off <<= 1) {
        int v = (t >= off) ? lds[t - off] : 0;
        __syncthreads();
        lds[t] += v;
        __syncthreads();
    }
    int base = lds[t] - s;   // exclusive prefix of this thread's chunk
    offsets[t * 4 + 0] = base;
    offsets[t * 4 + 1] = base + c[0];
    offsets[t * 4 + 2] = base + c[0] + c[1];
    offsets[t * 4 + 3] = base + c[0] + c[1] + c[2];
    if (t == 1023) offsets[4096] = lds[1023];
}

// ----------------------------------------- bucket fill (index atomics only)
__global__ __launch_bounds__(256) void bucket_fill_kernel(
    const int* __restrict__ idxw, const int* __restrict__ offsets,
    int* __restrict__ fill, int* __restrict__ bucket_list)
{
    int j = blockIdx.x * 256 + threadIdx.x;   // grid exact
    int code = idxw[j];
    int pos = atomicAdd(&fill[code], 1);
    bucket_list[offsets[code] + pos] = j / 3;
}

// --------------- per-code segmented sum: dw, new_ema_w, updated_embeddings
__global__ __launch_bounds__(64) void codeupd_kernel(
    const int* __restrict__ offsets, const int* __restrict__ bucket_list,
    const float* __restrict__ flat, const float* __restrict__ emaw,
    const float* __restrict__ ncs, float* __restrict__ nemaw,
    float* __restrict__ upd)
{
    int k = blockIdx.x;
    int lane = threadIdx.x;
    int beg = offsets[k], end = offsets[k + 1];
    float4 acc = {0.0f, 0.0f, 0.0f, 0.0f};
    for (int t = beg; t < end; t++) {
        int n = bucket_list[t];
        float4 v = *(const float4*)&flat[(size_t)n * DIM + lane * 4];
        acc.x += v.x; acc.y += v.y; acc.z += v.z; acc.w += v.w;
    }
    float4 w = *(const float4*)&emaw[(size_t)k * DIM + lane * 4];
    float4 nm;
    nm.x = 0.99f * w.x + 0.01f * acc.x;
    nm.y = 0.99f * w.y + 0.01f * acc.y;
    nm.z = 0.99f * w.z + 0.01f * acc.z;
    nm.w = 0.99f * w.w + 0.01f * acc.w;
    *(float4*)&nemaw[(size_t)k * DIM + lane * 4] = nm;
    float inv = ncs[k];
    float4 u = {nm.x / inv, nm.y / inv, nm.z / inv, nm.w / inv};
    *(float4*)&upd[(size_t)k * DIM + lane * 4] = u;
}

// ------------------------------------------------------------- loss reduce
__global__ __launch_bounds__(1024) void loss_reduce_kernel(
    const float* __restrict__ lp, float* __restrict__ out)
{
    __shared__ float ls[16];
    int t = threadIdx.x;
    float s = lp[t] + lp[t + 1024] + lp[t + 2048] + lp[t + 3072];
    #pragma unroll
    for (int off = 32; off; off >>= 1) s += __shfl_down(s, off);
    if ((t & 63) == 0) ls[t >> 6] = s;
    __syncthreads();
    if (t == 0) {
        float tot = 0.0f;
        #pragma unroll
        for (int i = 0; i < 16; i++) tot += ls[i];
        out[O_LOSS] = 0.25f * tot / (float)(N_ROWS * TOPK * DIM);
    }
}

// ------------------------------------------------------------- perplexity
__global__ void final_kernel(const float* __restrict__ scalars, float* __restrict__ out)
{
    out[O_PERP] = expf(-scalars[2]);
}

extern "C" void kernel_launch(void* const* d_in, const int* in_sizes, int n_in,
                              void* d_out, int out_size, void* d_ws, size_t ws_size,
                              hipStream_t stream)
{
    const float* inputs = (const float*)d_in[0];   // [16,1024,256]
    const float* emb    = (const float*)d_in[1];   // [4096,256]
    const float* ecs    = (const float*)d_in[2];   // [4096]
    const float* emaw   = (const float*)d_in[3];   // [4096,256]
    float* out = (float*)d_out;
    char* ws = (char*)d_ws;

    int*   idxw        = (int*)ws;                  // 49152 ints
    int*   bucket_list = (int*)(ws + 196608);       // 49152 ints
    float* counts      = (float*)(ws + 393216);     // 4096 f
    int*   offsets     = (int*)(ws + 409600);       // 4097 ints
    int*   fill        = (int*)(ws + 430080);       // 4096 ints
    float* xn          = (float*)(ws + 446464);     // 16384 f
    float* en          = (float*)(ws + 512000);     // 4096 f
    float* scalars     = (float*)(ws + 528384);     // 8 f
    float* loss_part   = (float*)(ws + 528448);     // 4096 f

    hipMemsetAsync(counts, 0, KC * sizeof(float), stream);
    hipMemsetAsync(fill, 0, KC * sizeof(int), stream);
    hipMemsetAsync(scalars, 0, 8 * sizeof(float), stream);

    rownorm_kernel<<<N_ROWS / 4, 256, 0, stream>>>(inputs, xn, N_ROWS);
    rownorm_kernel<<<KC / 4, 256, 0, stream>>>(emb, en, KC);

    gemm_dist_kernel<<<dim3(KC / BN, N_ROWS / BM), 256, 0, stream>>>(
        inputs, emb, xn, en, out + O_DIST);

    top3_kernel<<<N_ROWS / 4, 256, 0, stream>>>(
        out + O_DIST, idxw, out + O_IDX, counts, loss_part);

    kstage1_kernel<<<KC / 256, 256, 0, stream>>>(counts, ecs, out + O_AVGP, scalars);
    kstage2_kernel<<<KC / 256, 256, 0, stream>>>(counts, ecs, scalars, out + O_NCS);
    scan_kernel<<<1, 1024, 0, stream>>>(counts, offsets);
    bucket_fill_kernel<<<(N_ROWS * TOPK) / 256, 256, 0, stream>>>(
        idxw, offsets, fill, bucket_list);
    codeupd_kernel<<<KC, 64, 0, stream>>>(
        offsets, bucket_list, inputs, emaw, out + O_NCS,
        out + O_NEMAW, out + O_UPD);
    quant_copy_kernel<<<(N_ROWS * TOPK) / 4, 256, 0, stream>>>(
        idxw, emb, out + O_QUANT);

    loss_reduce_kernel<<<1, 1024, 0, stream>>>(loss_part, out);
    final_kernel<<<1, 1, 0, stream>>>(scalars, out);
}